// Round 1
// baseline (16070.848 us; speedup 1.0000x reference)
//
#include <hip/hip_runtime.h>
#include <math.h>

#define BB   4
#define SS   64
#define DD   512
#define HH   8
#define DHH  64
#define DFFF 2048
#define LL   2
#define VV   32128
#define TT   16
#define NEGB (-1e9f)
#define EPSV 1e-6f

// ---------------- embed gather: x[row,:] = emb[ids[row],:] ----------------
__global__ void k_embed(const int* __restrict__ ids, const float* __restrict__ emb,
                        float* __restrict__ x) {
    int row = blockIdx.x;            // 0..B*S-1
    int tid = threadIdx.x;           // 128
    int id  = ids[row];
    const float4* src = (const float4*)(emb + (size_t)id * DD);
    float4*       dst = (float4*)(x + (size_t)row * DD);
    dst[tid] = src[tid];
}

// ---------------- row-wise RMSNorm: h = x * rsqrt(mean(x^2)+eps) * ln -----
__global__ void k_rms(const float* __restrict__ x, const float* __restrict__ ln,
                      float* __restrict__ h, int K) {
    int row = blockIdx.x;
    int tid = threadIdx.x;           // 256
    const float* xr = x + (size_t)row * K;
    float local = 0.f;
    for (int k = tid; k < K; k += 256) { float v = xr[k]; local += v * v; }
    __shared__ float red[256];
    red[tid] = local; __syncthreads();
    for (int s = 128; s > 0; s >>= 1) { if (tid < s) red[tid] += red[tid + s]; __syncthreads(); }
    float scale = 1.0f / sqrtf(red[0] / K + EPSV);
    for (int k = tid; k < K; k += 256) h[(size_t)row * K + k] = xr[k] * scale * ln[k];
}

// ---------------- generic tiled fp32 GEMM: C[M,N] = A[M,K] @ W[K,N] -------
// optional residual add (res, stride N) and relu. grid (N/64, M/64), 256 thr.
#define TM 64
#define TN 64
#define TK 16
__global__ void k_gemm(const float* __restrict__ A, const float* __restrict__ W,
                       float* __restrict__ C, const float* __restrict__ res,
                       int M, int K, int N, int relu) {
    __shared__ float As[TK][TM + 1];
    __shared__ float Ws[TK][TN];
    int tid = threadIdx.x;
    int tr = tid / 16, tc = tid % 16;
    int row0 = blockIdx.y * TM, col0 = blockIdx.x * TN;
    float acc[4][4] = {};
    for (int k0 = 0; k0 < K; k0 += TK) {
        for (int i = tid; i < TM * TK; i += 256) {
            int r = i / TK, kk = i % TK;
            As[kk][r] = A[(size_t)(row0 + r) * K + k0 + kk];
        }
        for (int i = tid; i < TK * TN; i += 256) {
            int kk = i / TN, c = i % TN;
            Ws[kk][c] = W[(size_t)(k0 + kk) * N + col0 + c];
        }
        __syncthreads();
        #pragma unroll
        for (int kk = 0; kk < TK; kk++) {
            float a[4], b[4];
            #pragma unroll
            for (int j = 0; j < 4; j++) { a[j] = As[kk][tr * 4 + j]; b[j] = Ws[kk][tc * 4 + j]; }
            #pragma unroll
            for (int r = 0; r < 4; r++)
                #pragma unroll
                for (int c = 0; c < 4; c++) acc[r][c] += a[r] * b[c];
        }
        __syncthreads();
    }
    #pragma unroll
    for (int r = 0; r < 4; r++)
        #pragma unroll
        for (int c = 0; c < 4; c++) {
            int gr = row0 + tr * 4 + r, gc = col0 + tc * 4 + c;
            float v = acc[r][c];
            if (res) v += res[(size_t)gr * N + gc];
            if (relu) v = fmaxf(v, 0.f);
            C[(size_t)gr * N + gc] = v;
        }
}

// ---------------- encoder self-attention, one block per (b,h) -------------
__global__ void k_enc_attn(const float* __restrict__ qkv, const float* __restrict__ mask,
                           float* __restrict__ out) {
    int bh = blockIdx.x; int b = bh / HH, h = bh % HH;
    int tid = threadIdx.x;           // 256 = 4 waves
    int lane = tid & 63, wave = tid >> 6;
    __shared__ float qq[SS][DHH + 1], kk[SS][DHH + 1], vv[SS][DHH + 1];
    const size_t BSD = (size_t)BB * SS * DD;
    for (int i = tid; i < SS * DHH; i += 256) {
        int s = i >> 6, d = i & 63;
        size_t src = (size_t)(b * SS + s) * DD + h * DHH + d;
        qq[s][d] = qkv[src];
        kk[s][d] = qkv[BSD + src];
        vv[s][d] = qkv[2 * BSD + src];
    }
    __syncthreads();
    float bias = (1.0f - mask[b * SS + lane]) * NEGB;
    for (int r = 0; r < 16; r++) {
        int s = wave * 16 + r;
        float sc = 0.f;
        for (int i = 0; i < DHH; i++) sc += qq[s][i] * kk[lane][i];
        sc = sc * 0.125f + bias;
        float m = sc;
        for (int o = 32; o > 0; o >>= 1) m = fmaxf(m, __shfl_xor(m, o));
        float e = expf(sc - m);
        float sum = e;
        for (int o = 32; o > 0; o >>= 1) sum += __shfl_xor(sum, o);
        float p = e / sum;
        float acc = 0.f;
        for (int t2 = 0; t2 < SS; t2++) acc += __shfl(p, t2) * vv[t2][lane];
        out[(size_t)(b * SS + s) * DD + h * DHH + lane] = acc;
    }
}

// ---------------- decoder small-M (M=4) GEMM, up to 3 weight mats ---------
// grid.x = numW * (N/64), 256 threads. Optional RMS on A (ln), residual, relu.
__global__ void k_gemm4(const float* __restrict__ A, int K, const float* __restrict__ ln,
                        const float* __restrict__ w0, float* __restrict__ o0, int os0,
                        const float* __restrict__ w1, float* __restrict__ o1, int os1,
                        const float* __restrict__ w2, float* __restrict__ o2, int os2,
                        int N, const float* __restrict__ res, int relu) {
    __shared__ float hA[4 * 2048];
    __shared__ float wred[4][4][64];
    int tid = threadIdx.x;
    int lane = tid & 63;
    int wv = tid >> 6;               // wave id = k-group = staged batch row
    int nblk = N >> 6;
    int wsel = blockIdx.x / nblk;
    int cb = blockIdx.x - wsel * nblk;
    const float* W; float* O; int ostr;
    if (wsel == 0)      { W = w0; O = o0; ostr = os0; }
    else if (wsel == 1) { W = w1; O = o1; ostr = os1; }
    else                { W = w2; O = o2; ostr = os2; }
    {   // stage h[b=wv][:]
        const float* ar = A + (size_t)wv * K;
        if (ln) {
            float local = 0.f;
            for (int k = lane; k < K; k += 64) { float x = ar[k]; local += x * x; }
            for (int o = 32; o > 0; o >>= 1) local += __shfl_xor(local, o);
            float scale = 1.0f / sqrtf(local / K + EPSV);
            for (int k = lane; k < K; k += 64) hA[wv * K + k] = ar[k] * scale * ln[k];
        } else {
            for (int k = lane; k < K; k += 64) hA[wv * K + k] = ar[k];
        }
    }
    __syncthreads();
    int col = (cb << 6) + lane;
    int kpw = K >> 2;
    int k0 = wv * kpw;
    float a0 = 0.f, a1 = 0.f, a2 = 0.f, a3 = 0.f;
    for (int k = k0; k < k0 + kpw; k++) {
        float w = W[(size_t)k * N + col];
        a0 += hA[0 * K + k] * w;
        a1 += hA[1 * K + k] * w;
        a2 += hA[2 * K + k] * w;
        a3 += hA[3 * K + k] * w;
    }
    wred[wv][0][lane] = a0; wred[wv][1][lane] = a1;
    wred[wv][2][lane] = a2; wred[wv][3][lane] = a3;
    __syncthreads();
    // wave wv writes batch row wv
    float v = wred[0][wv][lane] + wred[1][wv][lane] + wred[2][wv][lane] + wred[3][wv][lane];
    if (res) v += res[(size_t)wv * ostr + col];
    if (relu) v = fmaxf(v, 0.f);
    O[(size_t)wv * ostr + col] = v;
}

// ---------------- decoder self-attention (incremental, pos p) -------------
__global__ void k_dec_self(const float* __restrict__ q, const float* __restrict__ sK,
                           const float* __restrict__ sV, float* __restrict__ out,
                           int l, int p) {
    int bh = blockIdx.x; int b = bh / HH, h = bh % HH;
    int lane = threadIdx.x;          // 64
    const float* qv = q + (size_t)b * DD + h * DHH;
    float sc = -INFINITY;
    if (lane <= p) {
        const float* kr = sK + (((size_t)(l * BB + b)) * TT + lane) * DD + h * DHH;
        float s2 = 0.f;
        for (int i = 0; i < DHH; i++) s2 += qv[i] * kr[i];
        sc = s2 * 0.125f;
    }
    float m = sc;
    for (int o = 32; o > 0; o >>= 1) m = fmaxf(m, __shfl_xor(m, o));
    float e = (lane <= p) ? expf(sc - m) : 0.f;
    float sum = e;
    for (int o = 32; o > 0; o >>= 1) sum += __shfl_xor(sum, o);
    float pr = e / sum;
    float acc = 0.f;
    for (int j = 0; j <= p; j++) {
        float pj = __shfl(pr, j);
        acc += pj * sV[(((size_t)(l * BB + b)) * TT + j) * DD + h * DHH + lane];
    }
    out[(size_t)b * DD + h * DHH + lane] = acc;
}

// ---------------- decoder cross-attention (64 encoder keys) ---------------
__global__ void k_dec_cross(const float* __restrict__ q, const float* __restrict__ cK,
                            const float* __restrict__ cV, const float* __restrict__ mask,
                            float* __restrict__ out, int l) {
    int bh = blockIdx.x; int b = bh / HH, h = bh % HH;
    int lane = threadIdx.x;          // 64
    const float* qv = q + (size_t)b * DD + h * DHH;
    const float* kr = cK + (((size_t)(l * BB + b)) * SS + lane) * DD + h * DHH;
    float s2 = 0.f;
    for (int i = 0; i < DHH; i++) s2 += qv[i] * kr[i];
    float sc = s2 * 0.125f + (1.0f - mask[b * SS + lane]) * NEGB;
    float m = sc;
    for (int o = 32; o > 0; o >>= 1) m = fmaxf(m, __shfl_xor(m, o));
    float e = expf(sc - m);
    float sum = e;
    for (int o = 32; o > 0; o >>= 1) sum += __shfl_xor(sum, o);
    float pr = e / sum;
    float acc = 0.f;
    for (int j = 0; j < SS; j++) {
        float pj = __shfl(pr, j);
        acc += pj * cV[(((size_t)(l * BB + b)) * SS + j) * DD + h * DHH + lane];
    }
    out[(size_t)b * DD + h * DHH + lane] = acc;
}

// ---------------- lm_head: logits[b,v] = rms(xd,lnf)[b,:] . W[:,v] --------
__global__ void k_lmhead(const float* __restrict__ xd, const float* __restrict__ lnf,
                         const float* __restrict__ Wlm, float* __restrict__ logits) {
    __shared__ float hA[4][DD];
    __shared__ float red[128];
    int tid = threadIdx.x;           // 128
    for (int b = 0; b < 4; b++) {
        float local = 0.f;
        for (int k = tid; k < DD; k += 128) { float v = xd[b * DD + k]; local += v * v; }
        red[tid] = local; __syncthreads();
        for (int s = 64; s > 0; s >>= 1) { if (tid < s) red[tid] += red[tid + s]; __syncthreads(); }
        float scale = 1.0f / sqrtf(red[0] / DD + EPSV);
        for (int k = tid; k < DD; k += 128) hA[b][k] = xd[b * DD + k] * scale * lnf[k];
        __syncthreads();
    }
    int col = blockIdx.x * 128 + tid;
    float a0 = 0.f, a1 = 0.f, a2 = 0.f, a3 = 0.f;
    for (int k = 0; k < DD; k++) {
        float w = Wlm[(size_t)k * VV + col];
        a0 += hA[0][k] * w; a1 += hA[1][k] * w; a2 += hA[2][k] * w; a3 += hA[3][k] * w;
    }
    logits[0 * (size_t)VV + col] = a0;
    logits[1 * (size_t)VV + col] = a1;
    logits[2 * (size_t)VV + col] = a2;
    logits[3 * (size_t)VV + col] = a3;
}

// ---------------- softmax over V + argmax flag, one block per b -----------
__global__ void k_softmax(const float* __restrict__ logits, float* __restrict__ outp, int t) {
    int b = blockIdx.x;
    int tid = threadIdx.x;           // 256
    const float* lg = logits + (size_t)b * VV;
    __shared__ float rmax[256]; __shared__ int ridx[256]; __shared__ float rsum[256];
    float m = -INFINITY; int mi = 0;
    for (int v = tid; v < VV; v += 256) { float x = lg[v]; if (x > m) { m = x; mi = v; } }
    rmax[tid] = m; ridx[tid] = mi; __syncthreads();
    for (int s = 128; s > 0; s >>= 1) {
        if (tid < s) {
            float om = rmax[tid + s]; int oi = ridx[tid + s];
            if (om > rmax[tid] || (om == rmax[tid] && oi < ridx[tid])) { rmax[tid] = om; ridx[tid] = oi; }
        }
        __syncthreads();
    }
    float M = rmax[0]; int amax = ridx[0];
    float sum = 0.f;
    for (int v = tid; v < VV; v += 256) sum += expf(lg[v] - M);
    rsum[tid] = sum; __syncthreads();
    for (int s = 128; s > 0; s >>= 1) { if (tid < s) rsum[tid] += rsum[tid + s]; __syncthreads(); }
    float inv = 1.0f / rsum[0];
    float* po = outp + ((size_t)b * TT + t) * VV;
    for (int v = tid; v < VV; v += 256) po[v] = expf(lg[v] - M) * inv;
    if (tid == 0) outp[(size_t)BB * TT * VV + b * TT + t] = (amax == 0) ? 1.0f : 0.0f;
}

// ---------------- probs @ emb, split-K stage 1 ----------------------------
#define NCH 64
#define CHV (VV / NCH)               // 502
__global__ void k_embmul1(const float* __restrict__ outp, const float* __restrict__ emb,
                          float* __restrict__ partial, int t) {
    int c = blockIdx.x;              // 64 chunks
    int tid = threadIdx.x;           // 256
    __shared__ float pl[4][CHV];
    int v0 = c * CHV;
    for (int i = tid; i < 4 * CHV; i += 256) {
        int b = i / CHV, j = i % CHV;
        pl[b][j] = outp[((size_t)b * TT + t) * VV + v0 + j];
    }
    __syncthreads();
    float acc[4][2] = {};
    for (int j = 0; j < CHV; j++) {
        const float* er = emb + (size_t)(v0 + j) * DD;
        float e0 = er[tid], e1 = er[tid + 256];
        #pragma unroll
        for (int b = 0; b < 4; b++) { acc[b][0] += pl[b][j] * e0; acc[b][1] += pl[b][j] * e1; }
    }
    float* pp = partial + (size_t)c * BB * DD;
    #pragma unroll
    for (int b = 0; b < 4; b++) { pp[b * DD + tid] = acc[b][0]; pp[b * DD + tid + 256] = acc[b][1]; }
}

// ---------------- stage 2: reduce partials into xd ------------------------
__global__ void k_embmul2(const float* __restrict__ partial, float* __restrict__ xd) {
    int id = blockIdx.x * 256 + threadIdx.x;   // 2048
    float acc = 0.f;
    for (int c = 0; c < NCH; c++) acc += partial[(size_t)c * BB * DD + id];
    xd[id] = acc;
}

// ---------------- init decoder input: xd[b,:] = emb[PAD=0,:] --------------
__global__ void k_init_xd(const float* __restrict__ emb, float* __restrict__ xd) {
    int tid = blockIdx.x * 256 + threadIdx.x;  // 2048
    xd[tid] = emb[tid & (DD - 1)];
}

extern "C" void kernel_launch(void* const* d_in, const int* in_sizes, int n_in,
                              void* d_out, int out_size, void* d_ws, size_t ws_size,
                              hipStream_t stream) {
    const int*   ids     = (const int*)  d_in[0];
    const float* mask    = (const float*)d_in[1];
    const float* emb     = (const float*)d_in[2];
    const float* enc_wq  = (const float*)d_in[3];
    const float* enc_wk  = (const float*)d_in[4];
    const float* enc_wv  = (const float*)d_in[5];
    const float* enc_wo  = (const float*)d_in[6];
    const float* enc_ln1 = (const float*)d_in[7];
    const float* enc_w1  = (const float*)d_in[8];
    const float* enc_w2  = (const float*)d_in[9];
    const float* enc_ln2 = (const float*)d_in[10];
    const float* enc_lnf = (const float*)d_in[11];
    const float* dec_sq  = (const float*)d_in[12];
    const float* dec_sk  = (const float*)d_in[13];
    const float* dec_sv  = (const float*)d_in[14];
    const float* dec_so  = (const float*)d_in[15];
    const float* dec_ln1 = (const float*)d_in[16];
    const float* dec_cq  = (const float*)d_in[17];
    const float* dec_ck  = (const float*)d_in[18];
    const float* dec_cv  = (const float*)d_in[19];
    const float* dec_co  = (const float*)d_in[20];
    const float* dec_ln2 = (const float*)d_in[21];
    const float* dec_w1  = (const float*)d_in[22];
    const float* dec_w2  = (const float*)d_in[23];
    const float* dec_ln3 = (const float*)d_in[24];
    const float* dec_lnf = (const float*)d_in[25];
    const float* lm_head = (const float*)d_in[26];

    float* out = (float*)d_out;
    float* ws  = (float*)d_ws;

    const size_t BSD = (size_t)BB * SS * DD;     // 131072
    float* xe      = ws;                          // B*S*D
    float* buf1    = xe + BSD;                    // B*S*DFF (qkv / ffn1)
    float* hbuf    = buf1 + (size_t)BB * SS * DFFF;   // B*S*D
    float* attbuf  = hbuf + BSD;                  // B*S*D
    float* cK      = attbuf + BSD;                // L*B*S*D
    float* cV      = cK + (size_t)LL * BSD;       // L*B*S*D
    float* sK      = cV + (size_t)LL * BSD;       // L*B*T*D
    float* sV      = sK + (size_t)LL * BB * TT * DD;
    float* xd      = sV + (size_t)LL * BB * TT * DD;  // B*D
    float* dq      = xd + BB * DD;                // B*D
    float* datt    = dq + BB * DD;                // B*D
    float* dff     = datt + BB * DD;              // B*DFF
    float* logits  = dff + BB * DFFF;             // B*V
    float* partial = logits + (size_t)BB * VV;    // NCH*B*D

    const size_t DD2 = (size_t)DD * DD;

    // ===================== ENCODER =====================
    k_embed<<<BB * SS, 128, 0, stream>>>(ids, emb, xe);
    for (int l = 0; l < LL; l++) {
        k_rms<<<BB * SS, 256, 0, stream>>>(xe, enc_ln1 + (size_t)l * DD, hbuf, DD);
        k_gemm<<<dim3(8, 4), 256, 0, stream>>>(hbuf, enc_wq + l * DD2, buf1,           nullptr, 256, 512, 512, 0);
        k_gemm<<<dim3(8, 4), 256, 0, stream>>>(hbuf, enc_wk + l * DD2, buf1 + BSD,     nullptr, 256, 512, 512, 0);
        k_gemm<<<dim3(8, 4), 256, 0, stream>>>(hbuf, enc_wv + l * DD2, buf1 + 2 * BSD, nullptr, 256, 512, 512, 0);
        k_enc_attn<<<BB * HH, 256, 0, stream>>>(buf1, mask, attbuf);
        k_gemm<<<dim3(8, 4), 256, 0, stream>>>(attbuf, enc_wo + l * DD2, xe, xe, 256, 512, 512, 0);
        k_rms<<<BB * SS, 256, 0, stream>>>(xe, enc_ln2 + (size_t)l * DD, hbuf, DD);
        k_gemm<<<dim3(32, 4), 256, 0, stream>>>(hbuf, enc_w1 + (size_t)l * DD * DFFF, buf1, nullptr, 256, 512, 2048, 1);
        k_gemm<<<dim3(8, 4), 256, 0, stream>>>(buf1, enc_w2 + (size_t)l * DFFF * DD, xe, xe, 256, 2048, 512, 0);
    }
    // final rms -> hs, then cross K/V caches (fixed for all decode steps)
    k_rms<<<BB * SS, 256, 0, stream>>>(xe, enc_lnf, hbuf, DD);
    for (int l = 0; l < LL; l++) {
        k_gemm<<<dim3(8, 4), 256, 0, stream>>>(hbuf, dec_ck + l * DD2, cK + l * BSD, nullptr, 256, 512, 512, 0);
        k_gemm<<<dim3(8, 4), 256, 0, stream>>>(hbuf, dec_cv + l * DD2, cV + l * BSD, nullptr, 256, 512, 512, 0);
    }

    // ===================== DECODER (incremental, KV-cached) =====================
    k_init_xd<<<8, 256, 0, stream>>>(emb, xd);
    for (int t = 0; t < TT; t++) {
        for (int l = 0; l < LL; l++) {
            // self qkv: q -> dq, k/v -> caches at position t
            k_gemm4<<<24, 256, 0, stream>>>(xd, 512, dec_ln1 + (size_t)l * DD,
                dec_sq + l * DD2, dq, DD,
                dec_sk + l * DD2, sK + (size_t)(l * BB * TT + t) * DD, TT * DD,
                dec_sv + l * DD2, sV + (size_t)(l * BB * TT + t) * DD, TT * DD,
                512, nullptr, 0);
            k_dec_self<<<BB * HH, 64, 0, stream>>>(dq, sK, sV, datt, l, t);
            k_gemm4<<<8, 256, 0, stream>>>(datt, 512, nullptr,
                dec_so + l * DD2, xd, DD, nullptr, nullptr, 0, nullptr, nullptr, 0,
                512, xd, 0);
            // cross attention
            k_gemm4<<<8, 256, 0, stream>>>(xd, 512, dec_ln2 + (size_t)l * DD,
                dec_cq + l * DD2, dq, DD, nullptr, nullptr, 0, nullptr, nullptr, 0,
                512, nullptr, 0);
            k_dec_cross<<<BB * HH, 64, 0, stream>>>(dq, cK, cV, mask, datt, l);
            k_gemm4<<<8, 256, 0, stream>>>(datt, 512, nullptr,
                dec_co + l * DD2, xd, DD, nullptr, nullptr, 0, nullptr, nullptr, 0,
                512, xd, 0);
            // FFN
            k_gemm4<<<32, 256, 0, stream>>>(xd, 512, dec_ln3 + (size_t)l * DD,
                dec_w1 + (size_t)l * DD * DFFF, dff, DFFF, nullptr, nullptr, 0, nullptr, nullptr, 0,
                2048, nullptr, 1);
            k_gemm4<<<8, 256, 0, stream>>>(dff, 2048, nullptr,
                dec_w2 + (size_t)l * DFFF * DD, xd, DD, nullptr, nullptr, 0, nullptr, nullptr, 0,
                512, xd, 0);
        }
        k_lmhead<<<VV / 128, 128, 0, stream>>>(xd, dec_lnf, lm_head, logits);
        k_softmax<<<BB, 256, 0, stream>>>(logits, out, t);
        k_embmul1<<<NCH, 256, 0, stream>>>(out, emb, partial, t);
        k_embmul2<<<8, 256, 0, stream>>>(partial, xd);
    }
}